// Round 4
// baseline (709.172 us; speedup 1.0000x reference)
//
#include <hip/hip_runtime.h>
#include <hip/hip_bf16.h>

typedef __hip_bfloat16 bf16;
typedef __attribute__((ext_vector_type(8))) short bshort8;  // 8 x bf16 (4 VGPRs)
typedef __attribute__((ext_vector_type(4))) float f32x4;    // MFMA accumulator

#define GLL16(gsrc, ldst)                                                      \
  __builtin_amdgcn_global_load_lds(                                            \
      (const __attribute__((address_space(1))) void*)(gsrc),                   \
      (__attribute__((address_space(3))) void*)(ldst), 16, 0, 0)

#define MEMFENCE asm volatile("" ::: "memory")
#define BARRIER                                                                \
  do {                                                                         \
    MEMFENCE;                                                                  \
    __builtin_amdgcn_s_barrier();                                              \
    MEMFENCE;                                                                  \
  } while (0)
#define WAIT_LGKM0 asm volatile("s_waitcnt lgkmcnt(0)" ::: "memory")
#define WAIT_VM(n) asm volatile("s_waitcnt vmcnt(" #n ")" ::: "memory")

// ---------------- cast f32 -> bf16, vectorized ----------------
__global__ __launch_bounds__(256) void cast_f32_bf16(const float* __restrict__ src,
                                                     bf16* __restrict__ dst, int n4) {
  int stride = gridDim.x * blockDim.x;
  const float4* s4 = reinterpret_cast<const float4*>(src);
  __hip_bfloat162* d2 = reinterpret_cast<__hip_bfloat162*>(dst);
  for (int i = blockIdx.x * blockDim.x + threadIdx.x; i < n4; i += stride) {
    float4 v = s4[i];
    d2[2 * i]     = __float22bfloat162_rn(make_float2(v.x, v.y));
    d2[2 * i + 1] = __float22bfloat162_rn(make_float2(v.z, v.w));
  }
}

// ---------------- x (b,i,m) f32 -> Xt (b,m,i) bf16 ----------------
__global__ __launch_bounds__(256) void transpose_cast_x(const float* __restrict__ x,
                                                        bf16* __restrict__ Xt) {
  __shared__ bf16 t[64][65];
  int b = blockIdx.z;
  int m0 = blockIdx.x * 64;
  int i0 = blockIdx.y * 64;
  int tx = threadIdx.x & 63;
  int ty = threadIdx.x >> 6;
  for (int ii = ty; ii < 64; ii += 4)
    t[ii][tx] = __float2bfloat16(x[(size_t)(b * 256 + i0 + ii) * 4096 + m0 + tx]);
  __syncthreads();
  for (int mm = ty; mm < 64; mm += 4)
    Xt[(size_t)(b * 4096 + m0 + mm) * 256 + i0 + tx] = t[tx][mm];
}

// ---------------- Theta slots: [0]=th0+th4, [1..3]=th1..3, [4..6]=th5..7 ----------------
__global__ __launch_bounds__(256) void build_theta(const float* __restrict__ th,
                                                   bf16* __restrict__ Tall) {
  int idx = blockIdx.x * 256 + threadIdx.x;  // 7*65536 exactly
  int s = idx >> 16;
  int oi = idx & 65535;
  float v;
  if (s == 0)      v = th[oi * 8 + 0] + th[oi * 8 + 4];
  else if (s <= 3) v = th[oi * 8 + s];
  else             v = th[oi * 8 + s + 1];
  Tall[idx] = __float2bfloat16(v);
}

// ---------------- 128^2 m97-style bt-GEMM (for shallow-K chan GEMMs) ----------------
__device__ __forceinline__ void gemm_bt_tile(const bf16* __restrict__ A,
                                             const bf16* __restrict__ Bm, int K,
                                             bf16* __restrict__ Cb) {
  __shared__ __align__(16) bf16 As[128 * 32];
  __shared__ __align__(16) bf16 Bs[128 * 32];
  const int tid = threadIdx.x;
  const int lane = tid & 63;
  const int w = tid >> 6;
  const int wr = w >> 1, wc = w & 1;

  const int srow = w * 32 + (lane >> 2);
  const int scol = (lane & 3) * 8;
  bf16* ldsA0 = &As[(w * 32 + 0) * 32];
  bf16* ldsA1 = &As[(w * 32 + 16) * 32];
  bf16* ldsB0 = &Bs[(w * 32 + 0) * 32];
  bf16* ldsB1 = &Bs[(w * 32 + 16) * 32];
  const bf16* aptr0 = A + (size_t)srow * K + scol;
  const bf16* aptr1 = A + (size_t)(srow + 16) * K + scol;
  const bf16* bptr0 = Bm + (size_t)srow * K + scol;
  const bf16* bptr1 = Bm + (size_t)(srow + 16) * K + scol;

  f32x4 acc[4][4];
#pragma unroll
  for (int i = 0; i < 4; ++i)
#pragma unroll
    for (int j = 0; j < 4; ++j) acc[i][j] = (f32x4){0.f, 0.f, 0.f, 0.f};

  const int rsel = lane & 15;
  const int ksel = (lane >> 4) * 8;

  for (int kt = 0; kt < K; kt += 32) {
    GLL16(aptr0 + kt, ldsA0);
    GLL16(aptr1 + kt, ldsA1);
    GLL16(bptr0 + kt, ldsB0);
    GLL16(bptr1 + kt, ldsB1);
    __syncthreads();
    bshort8 av[4], bv[4];
#pragma unroll
    for (int m = 0; m < 4; ++m)
      av[m] = *reinterpret_cast<const bshort8*>(&As[(wr * 64 + m * 16 + rsel) * 32 + ksel]);
#pragma unroll
    for (int n = 0; n < 4; ++n)
      bv[n] = *reinterpret_cast<const bshort8*>(&Bs[(wc * 64 + n * 16 + rsel) * 32 + ksel]);
#pragma unroll
    for (int m = 0; m < 4; ++m)
#pragma unroll
      for (int n = 0; n < 4; ++n)
        acc[m][n] = __builtin_amdgcn_mfma_f32_16x16x32_bf16(av[m], bv[n], acc[m][n], 0, 0, 0);
    __syncthreads();
  }

  const int colf = lane & 15;
  const int rowf = (lane >> 4) * 4;
#pragma unroll
  for (int m = 0; m < 4; ++m) {
#pragma unroll
    for (int n = 0; n < 4; ++n) {
      int r0 = wr * 64 + m * 16 + rowf;
      int c = wc * 64 + n * 16 + colf;
#pragma unroll
      for (int r = 0; r < 4; ++r) {
        size_t off = (size_t)(r0 + r) * 4096 + c;
        Cb[off] = __float2bfloat16(acc[m][n][r]);
      }
    }
  }
}

// ---- all channel-mix GEMMs in ONE launch: u_k = Theta_k @ Xt^T for all slots ----
// z<48: k=1+z/16, chain=(z%16)>>3, b=z&7, slot = chain? k+3 : k, dst=U_k stacked rows
// z>=48: u0 (merged th0+th4), b=z-48, dst=U0
__global__ __launch_bounds__(256) void chan_all(const bf16* __restrict__ Tall,
                                                const bf16* __restrict__ Xt,
                                                bf16* __restrict__ U0,
                                                bf16* __restrict__ U1,
                                                bf16* __restrict__ U2,
                                                bf16* __restrict__ U3) {
  int rt = blockIdx.x;  // 0..1
  int ct = blockIdx.y;  // 0..31
  int z = blockIdx.z;   // 0..55
  int slot, b;
  bf16* Ubuf;
  size_t rowbase;
  if (z < 48) {
    int k = 1 + z / 16;
    int r = z % 16;
    int chain = r >> 3;
    b = r & 7;
    slot = chain ? k + 3 : k;
    Ubuf = (k == 1) ? U1 : ((k == 2) ? U2 : U3);
    rowbase = (size_t)(chain * 2048 + b * 256);
  } else {
    b = z - 48;
    slot = 0;
    Ubuf = U0;
    rowbase = (size_t)b * 256;
  }
  const bf16* A = Tall + (size_t)slot * 65536 + (size_t)rt * 128 * 256;
  const bf16* Bm = Xt + (size_t)b * 4096 * 256 + (size_t)ct * 128 * 256;
  bf16* dst = Ubuf + (rowbase + (size_t)rt * 128) * 4096 + ct * 128;
  gemm_bt_tile(A, Bm, 256, dst);
}

// ================= 256^2 8-phase bt-GEMM with 1-phase register read-ahead =================
// C(256x256) = A(256xK) * B(256xK)^T-rows, ldc=4096. 8 waves (2Mx4N), per-wave 128x64.
// LDS 128KiB: buf{0,1} x {A0,A1,B0,B1} x 16KB. T2 swizzle (16B col-block ^= row&7),
// pre-swizzled global source + swizzled ds_read (involution, rule #21).
// Pipeline: phase p consumes frags read at p-1 top; issues p+1 frags before its MFMA,
// so the LDS pipe serves reads UNDER the MFMA cluster.
// Stage schedule (per it; t1=2it+1,t2=2it+2,t3=2it+3): p0:A(buf1,t1)x2  p1:B(0,0,t2)
// p2:B(0,1,t2),tail vmcnt(4|0-last)  p3:-  p4:A(0,0,t2)  p5:A(0,1,t2)  p6:B(1,0,t3),
// tail vmcnt(2)  p7:B(1,1,t3). WAR: every region re-staged >=1 barrier after all waves'
// read-drain (next-phase-top lgkmcnt0). RAW: p2/p6 counted vm-waits cover the p3/p7-top
// buffer-switch read-issues (in-order drain verified for first/steady/last iterations).
template <int EPI>  // 0: Cb = bf16(acc + Db) ; 2: rt<8 -> Cf=acc+Db+bias (Y), rt>=8 -> Cf2=acc (P1)
__global__ __launch_bounds__(512, 2) void gemm256(
    const bf16* __restrict__ Aall, const bf16* __restrict__ B0m,
    const bf16* __restrict__ B1m, bf16* __restrict__ Cb, float* __restrict__ Cf,
    float* __restrict__ Cf2, const bf16* __restrict__ Db,
    const float* __restrict__ bias, int K) {
  const int tid = threadIdx.x;
  const int lane = tid & 63;
  const int w = tid >> 6;          // wave 0..7
  const int wr = w >> 2, wc = w & 3;

  // T1: bijective XCD swizzle, 256 blocks
  int bid = blockIdx.x;
  int gid = (bid & 7) * 32 + (bid >> 3);
  const int rt = gid >> 4, ct = gid & 15;

  const bf16* Atile = Aall + (size_t)rt * 256 * K;
  const bf16* Btile = ((rt < 8) ? B0m : B1m) + (size_t)ct * 256 * K;

  __shared__ __align__(16) char lds_[131072];

  // staging: thread covers rows {tid>>3, +64}, swizzled 16B col (tid&7)^((tid>>3)&7)
  const int srow = tid >> 3;
  const int scol = (((tid & 7) ^ ((tid >> 3) & 7)) << 3);  // elements
  const bf16* gA = Atile + (size_t)srow * K + scol;
  const bf16* gB = Btile + (size_t)srow * K + scol;

#define STAGE_A(buf, half, kt)                                                 \
  do {                                                                         \
    char* l = &lds_[(buf)*65536 + (half)*16384 + w * 1024];                    \
    const bf16* g = gA + (size_t)((half)*128) * K + (size_t)(kt)*64;           \
    GLL16(g, l);                                                               \
    GLL16(g + (size_t)64 * K, l + 8192);                                       \
  } while (0)
#define STAGE_B(buf, half, kt)                                                 \
  do {                                                                         \
    char* l = &lds_[(buf)*65536 + 32768 + (half)*16384 + w * 1024];            \
    const bf16* g = gB + (size_t)((half)*128) * K + (size_t)(kt)*64;           \
    GLL16(g, l);                                                               \
    GLL16(g + (size_t)64 * K, l + 8192);                                       \
  } while (0)

  const int rsel = lane & 15;
  const int cbb = lane >> 4;   // 0..3
  const int xorv = rsel & 7;
  const int aBase = wr * 16384 + rsel * 128;
  const int bBase = 32768 + (wc >> 1) * 16384 + ((wc & 1) * 64 + rsel) * 128;
#define LDA(buf, mf, ks)                                                       \
  (*(const bshort8*)&lds_[(buf)*65536 + aBase + (mf)*2048 +                    \
                          (((((ks)*4) + cbb) ^ xorv) << 4)])
#define LDB(buf, nf, ks)                                                       \
  (*(const bshort8*)&lds_[(buf)*65536 + bBase + (nf)*2048 +                    \
                          (((((ks)*4) + cbb) ^ xorv) << 4)])

  f32x4 acc[8][4];
#pragma unroll
  for (int i = 0; i < 8; ++i)
#pragma unroll
    for (int j = 0; j < 4; ++j) acc[i][j] = (f32x4){0.f, 0.f, 0.f, 0.f};

  const int NT = K >> 6;   // 64-wide K tiles (64)
  const int NI = NT >> 1;  // iterations (32)

  // double-buffered fragment registers (static indexing only — rule #20)
  bshort8 afr0[2][2], afr1[2][2];  // by phase parity
  bshort8 bfr0[4][2], bfr1[4][2];  // by LDS buffer

#define RD_A(DST, BUF, Q)                                                      \
  do {                                                                         \
    DST[0][0] = LDA(BUF, (Q)*2 + 0, 0);                                        \
    DST[0][1] = LDA(BUF, (Q)*2 + 0, 1);                                        \
    DST[1][0] = LDA(BUF, (Q)*2 + 1, 0);                                        \
    DST[1][1] = LDA(BUF, (Q)*2 + 1, 1);                                        \
  } while (0)
#define RD_B(DST, BUF)                                                         \
  do {                                                                         \
    DST[0][0] = LDB(BUF, 0, 0); DST[0][1] = LDB(BUF, 0, 1);                    \
    DST[1][0] = LDB(BUF, 1, 0); DST[1][1] = LDB(BUF, 1, 1);                    \
    DST[2][0] = LDB(BUF, 2, 0); DST[2][1] = LDB(BUF, 2, 1);                    \
    DST[3][0] = LDB(BUF, 3, 0); DST[3][1] = LDB(BUF, 3, 1);                    \
  } while (0)

#define MFMA16(Q, AF, BF)                                                      \
  do {                                                                         \
    _Pragma("unroll") for (int mi = 0; mi < 2; ++mi)                           \
    _Pragma("unroll") for (int nf = 0; nf < 4; ++nf)                           \
    _Pragma("unroll") for (int ks = 0; ks < 2; ++ks)                           \
        acc[(Q)*2 + mi][nf] = __builtin_amdgcn_mfma_f32_16x16x32_bf16(         \
            AF[mi][ks], BF[nf][ks], acc[(Q)*2 + mi][nf], 0, 0, 0);             \
  } while (0)

#define PHASE_(Q, AF, BF, RDSTMT, STAGESTMT, TAILSTMT)                         \
  do {                                                                         \
    WAIT_LGKM0;                                                                \
    RDSTMT;                                                                    \
    STAGESTMT;                                                                 \
    BARRIER;                                                                   \
    __builtin_amdgcn_s_setprio(1);                                             \
    MFMA16(Q, AF, BF);                                                         \
    __builtin_amdgcn_s_setprio(0);                                             \
    TAILSTMT;                                                                  \
    BARRIER;                                                                   \
  } while (0)

  // prologue: tile0 -> buf0 (A+B), tile1's B -> buf1; then first frag reads
  STAGE_A(0, 0, 0); STAGE_A(0, 1, 0);
  STAGE_B(0, 0, 0); STAGE_B(0, 1, 0);
  STAGE_B(1, 0, 1); STAGE_B(1, 1, 1);
  WAIT_VM(4);   // drain buf0's 8, leave B-buf1's 4 in flight
  BARRIER;
  RD_B(bfr0, 0);
  RD_A(afr0, 0, 0);

  for (int it = 0; it < NI; ++it) {
    const int t1 = 2 * it + 1, t2 = 2 * it + 2, t3 = 2 * it + 3;
    const bool p2v = t2 < NT, p3v = t3 < NT, last = (it == NI - 1);
    PHASE_(0, afr0, bfr0, RD_A(afr1, 0, 1),
           { STAGE_A(1, 0, t1); STAGE_A(1, 1, t1); }, {});
    PHASE_(1, afr1, bfr0, RD_A(afr0, 0, 2), { if (p2v) STAGE_B(0, 0, t2); }, {});
    PHASE_(2, afr0, bfr0, RD_A(afr1, 0, 3), { if (p2v) STAGE_B(0, 1, t2); },
           { if (last) { WAIT_VM(0); } else { WAIT_VM(4); } });
    PHASE_(3, afr1, bfr0, { RD_B(bfr1, 1); RD_A(afr0, 1, 0); }, {}, {});
    PHASE_(0, afr0, bfr1, RD_A(afr1, 1, 1), { if (p2v) STAGE_A(0, 0, t2); }, {});
    PHASE_(1, afr1, bfr1, RD_A(afr0, 1, 2), { if (p2v) STAGE_A(0, 1, t2); }, {});
    PHASE_(2, afr0, bfr1, RD_A(afr1, 1, 3), { if (p3v) STAGE_B(1, 0, t3); },
           { WAIT_VM(2); });
    PHASE_(3, afr1, bfr1, { if (!last) { RD_B(bfr0, 0); RD_A(afr0, 0, 0); } },
           { if (p3v) STAGE_B(1, 1, t3); }, {});
  }

  // epilogue: C/D map col=lane&15, row=(lane>>4)*4+reg (verified m89/m91)
  const int colf = lane & 15;
  const int rowf = (lane >> 4) * 4;
  const size_t crow0 = (size_t)rt * 256 + wr * 128;
  const size_t ccol0 = (size_t)ct * 256 + wc * 64;
#pragma unroll
  for (int mf = 0; mf < 8; ++mf) {
#pragma unroll
    for (int nf = 0; nf < 4; ++nf) {
#pragma unroll
      for (int r = 0; r < 4; ++r) {
        size_t row = crow0 + mf * 16 + rowf + r;
        size_t col = ccol0 + nf * 16 + colf;
        size_t off = row * 4096 + col;
        float v = acc[mf][nf][r];
        if constexpr (EPI == 0) {
          v += __bfloat162float(Db[off]);
          Cb[off] = __float2bfloat16(v);
        } else {
          if (rt < 8) {
            v += __bfloat162float(Db[off]) + bias[row & 255];
            Cf[off] = v;
          } else {
            Cf2[(row - 2048) * 4096 + col] = v;
          }
        }
      }
    }
  }
#undef STAGE_A
#undef STAGE_B
#undef LDA
#undef LDB
#undef RD_A
#undef RD_B
#undef MFMA16
#undef PHASE_
}

// ---- Y += P1 ----
__global__ __launch_bounds__(256) void reduce_add(float* __restrict__ Y,
                                                  const float* __restrict__ P1) {
  float4* Y4 = (float4*)Y;
  const float4* P4 = (const float4*)P1;
  const int n4 = 2048 * 4096 / 4;
  int stride = gridDim.x * blockDim.x;
  for (int i = blockIdx.x * 256 + threadIdx.x; i < n4; i += stride) {
    float4 a = Y4[i];
    float4 b = P4[i];
    a.x += b.x; a.y += b.y; a.z += b.z; a.w += b.w;
    Y4[i] = a;
  }
}

extern "C" void kernel_launch(void* const* d_in, const int* in_sizes, int n_in,
                              void* d_out, int out_size, void* d_ws, size_t ws_size,
                              hipStream_t stream) {
  const float* Ll = (const float*)d_in[0];
  const float* Lu = (const float*)d_in[1];
  const float* x = (const float*)d_in[2];
  const float* th = (const float*)d_in[3];
  const float* bias = (const float*)d_in[4];
  float* Y = (float*)d_out;

  // Workspace budget: ws_size is 256 MiB (R3 overflowed it by 0.9 MB -> abort).
  // Layout total here = 235,798,528 B < R2-proven 252,575,744 B.
  char* ws = (char*)d_ws;
  const size_t SZ_L = (size_t)4096 * 4096 * 2;         // 33.5 MB bf16 4096x4096
  const size_t SZ_U = (size_t)4096 * 4096 * 2;         // 33.5 MB stacked 4096x4096 bf16
  const size_t SZ_X = (size_t)8 * 4096 * 256 * 2;      // 16.8 MB
  const size_t SZ_T = ((size_t)7 * 256 * 256 * 2 + 255) & ~(size_t)255;
  const size_t SZ_U0 = (size_t)2048 * 4096 * 2;        // 16.8 MB
  bf16* Llb = (bf16*)ws; ws += SZ_L;
  bf16* Lub = (bf16*)ws; ws += SZ_L;
  bf16* Xt  = (bf16*)ws; ws += SZ_X;
  bf16* Tall = (bf16*)ws; ws += SZ_T;
  bf16* U1 = (bf16*)ws; ws += SZ_U;
  bf16* U2 = (bf16*)ws; ws += SZ_U;
  bf16* U3 = (bf16*)ws; ws += SZ_U;   // reused as V2 output of g2
  bf16* U0 = (bf16*)ws; ws += SZ_U0;
  bf16* V1 = (bf16*)ws; ws += SZ_U;
  // P1 ALIASES V1: V1 is dead after g2 (its last reader); g3 writes P1 while
  // reading only U3/U0. 2048*4096*4 B == SZ_U exactly.
  float* P1 = (float*)V1;
  (void)ws_size; (void)in_sizes; (void)n_in; (void)out_size;

  cast_f32_bf16<<<2048, 256, 0, stream>>>(Ll, Llb, 4096 * 4096 / 4);
  cast_f32_bf16<<<2048, 256, 0, stream>>>(Lu, Lub, 4096 * 4096 / 4);
  transpose_cast_x<<<dim3(64, 4, 8), 256, 0, stream>>>(x, Xt);
  build_theta<<<1792, 256, 0, stream>>>(th, Tall);

  // all u_k in one launch
  chan_all<<<dim3(2, 32, 56), 256, 0, stream>>>(Tall, Xt, U0, U1, U2, U3);

  // Horner (both chains stacked as rows 0..2047 / 2048..4095):
  gemm256<0><<<256, 512, 0, stream>>>(U3, Llb, Lub, V1, nullptr, nullptr, U2,
                                      nullptr, 4096);  // V1 = L@U3 + U2
  gemm256<0><<<256, 512, 0, stream>>>(V1, Llb, Lub, U3, nullptr, nullptr, U1,
                                      nullptr, 4096);  // V2(=U3) = L@V1 + U1
  gemm256<2><<<256, 512, 0, stream>>>(U3, Llb, Lub, nullptr, Y, P1, U0, bias,
                                      4096);           // Y(chain0)+U0+bias ; P1(chain1)
  reduce_add<<<2048, 256, 0, stream>>>(Y, P1);
}

// Round 5
// 521.062 us; speedup vs baseline: 1.3610x; 1.3610x over previous
//
#include <hip/hip_runtime.h>
#include <hip/hip_bf16.h>

typedef __hip_bfloat16 bf16;
typedef __attribute__((ext_vector_type(8))) short bshort8;  // 8 x bf16 (4 VGPRs)
typedef __attribute__((ext_vector_type(4))) float f32x4;    // MFMA accumulator

#define GLL16(gsrc, ldst)                                                      \
  __builtin_amdgcn_global_load_lds(                                            \
      (const __attribute__((address_space(1))) void*)(gsrc),                   \
      (__attribute__((address_space(3))) void*)(ldst), 16, 0, 0)

#define MEMFENCE asm volatile("" ::: "memory")
#define BARRIER                                                                \
  do {                                                                         \
    MEMFENCE;                                                                  \
    __builtin_amdgcn_s_barrier();                                              \
    MEMFENCE;                                                                  \
  } while (0)
#define WAIT_LGKM0 asm volatile("s_waitcnt lgkmcnt(0)" ::: "memory")
#define WAIT_LGKM8 asm volatile("s_waitcnt lgkmcnt(8)" ::: "memory")
#define WAIT_VM(n) asm volatile("s_waitcnt vmcnt(" #n ")" ::: "memory")

// ---------------- cast f32 -> bf16, vectorized ----------------
__global__ __launch_bounds__(256) void cast_f32_bf16(const float* __restrict__ src,
                                                     bf16* __restrict__ dst, int n4) {
  int stride = gridDim.x * blockDim.x;
  const float4* s4 = reinterpret_cast<const float4*>(src);
  __hip_bfloat162* d2 = reinterpret_cast<__hip_bfloat162*>(dst);
  for (int i = blockIdx.x * blockDim.x + threadIdx.x; i < n4; i += stride) {
    float4 v = s4[i];
    d2[2 * i]     = __float22bfloat162_rn(make_float2(v.x, v.y));
    d2[2 * i + 1] = __float22bfloat162_rn(make_float2(v.z, v.w));
  }
}

// ---------------- x (b,i,m) f32 -> Xt (b,m,i) bf16 ----------------
__global__ __launch_bounds__(256) void transpose_cast_x(const float* __restrict__ x,
                                                        bf16* __restrict__ Xt) {
  __shared__ bf16 t[64][65];
  int b = blockIdx.z;
  int m0 = blockIdx.x * 64;
  int i0 = blockIdx.y * 64;
  int tx = threadIdx.x & 63;
  int ty = threadIdx.x >> 6;
  for (int ii = ty; ii < 64; ii += 4)
    t[ii][tx] = __float2bfloat16(x[(size_t)(b * 256 + i0 + ii) * 4096 + m0 + tx]);
  __syncthreads();
  for (int mm = ty; mm < 64; mm += 4)
    Xt[(size_t)(b * 4096 + m0 + mm) * 256 + i0 + tx] = t[tx][mm];
}

// ---------------- Theta slots: [0]=th0+th4, [1..3]=th1..3, [4..6]=th5..7 ----------------
__global__ __launch_bounds__(256) void build_theta(const float* __restrict__ th,
                                                   bf16* __restrict__ Tall) {
  int idx = blockIdx.x * 256 + threadIdx.x;  // 7*65536 exactly
  int s = idx >> 16;
  int oi = idx & 65535;
  float v;
  if (s == 0)      v = th[oi * 8 + 0] + th[oi * 8 + 4];
  else if (s <= 3) v = th[oi * 8 + s];
  else             v = th[oi * 8 + s + 1];
  Tall[idx] = __float2bfloat16(v);
}

// ---------------- 128^2 m97-style bt-GEMM (for shallow-K chan GEMMs) ----------------
__device__ __forceinline__ void gemm_bt_tile(const bf16* __restrict__ A,
                                             const bf16* __restrict__ Bm, int K,
                                             bf16* __restrict__ Cb) {
  __shared__ __align__(16) bf16 As[128 * 32];
  __shared__ __align__(16) bf16 Bs[128 * 32];
  const int tid = threadIdx.x;
  const int lane = tid & 63;
  const int w = tid >> 6;
  const int wr = w >> 1, wc = w & 1;

  const int srow = w * 32 + (lane >> 2);
  const int scol = (lane & 3) * 8;
  bf16* ldsA0 = &As[(w * 32 + 0) * 32];
  bf16* ldsA1 = &As[(w * 32 + 16) * 32];
  bf16* ldsB0 = &Bs[(w * 32 + 0) * 32];
  bf16* ldsB1 = &Bs[(w * 32 + 16) * 32];
  const bf16* aptr0 = A + (size_t)srow * K + scol;
  const bf16* aptr1 = A + (size_t)(srow + 16) * K + scol;
  const bf16* bptr0 = Bm + (size_t)srow * K + scol;
  const bf16* bptr1 = Bm + (size_t)(srow + 16) * K + scol;

  f32x4 acc[4][4];
#pragma unroll
  for (int i = 0; i < 4; ++i)
#pragma unroll
    for (int j = 0; j < 4; ++j) acc[i][j] = (f32x4){0.f, 0.f, 0.f, 0.f};

  const int rsel = lane & 15;
  const int ksel = (lane >> 4) * 8;

  for (int kt = 0; kt < K; kt += 32) {
    GLL16(aptr0 + kt, ldsA0);
    GLL16(aptr1 + kt, ldsA1);
    GLL16(bptr0 + kt, ldsB0);
    GLL16(bptr1 + kt, ldsB1);
    __syncthreads();
    bshort8 av[4], bv[4];
#pragma unroll
    for (int m = 0; m < 4; ++m)
      av[m] = *reinterpret_cast<const bshort8*>(&As[(wr * 64 + m * 16 + rsel) * 32 + ksel]);
#pragma unroll
    for (int n = 0; n < 4; ++n)
      bv[n] = *reinterpret_cast<const bshort8*>(&Bs[(wc * 64 + n * 16 + rsel) * 32 + ksel]);
#pragma unroll
    for (int m = 0; m < 4; ++m)
#pragma unroll
      for (int n = 0; n < 4; ++n)
        acc[m][n] = __builtin_amdgcn_mfma_f32_16x16x32_bf16(av[m], bv[n], acc[m][n], 0, 0, 0);
    __syncthreads();
  }

  const int colf = lane & 15;
  const int rowf = (lane >> 4) * 4;
#pragma unroll
  for (int m = 0; m < 4; ++m) {
#pragma unroll
    for (int n = 0; n < 4; ++n) {
      int r0 = wr * 64 + m * 16 + rowf;
      int c = wc * 64 + n * 16 + colf;
#pragma unroll
      for (int r = 0; r < 4; ++r) {
        size_t off = (size_t)(r0 + r) * 4096 + c;
        Cb[off] = __float2bfloat16(acc[m][n][r]);
      }
    }
  }
}

// ---- all channel-mix GEMMs in ONE launch ----
__global__ __launch_bounds__(256) void chan_all(const bf16* __restrict__ Tall,
                                                const bf16* __restrict__ Xt,
                                                bf16* __restrict__ U0,
                                                bf16* __restrict__ U1,
                                                bf16* __restrict__ U2,
                                                bf16* __restrict__ U3) {
  int rt = blockIdx.x;  // 0..1
  int ct = blockIdx.y;  // 0..31
  int z = blockIdx.z;   // 0..55
  int slot, b;
  bf16* Ubuf;
  size_t rowbase;
  if (z < 48) {
    int k = 1 + z / 16;
    int r = z % 16;
    int chain = r >> 3;
    b = r & 7;
    slot = chain ? k + 3 : k;
    Ubuf = (k == 1) ? U1 : ((k == 2) ? U2 : U3);
    rowbase = (size_t)(chain * 2048 + b * 256);
  } else {
    b = z - 48;
    slot = 0;
    Ubuf = U0;
    rowbase = (size_t)b * 256;
  }
  const bf16* A = Tall + (size_t)slot * 65536 + (size_t)rt * 128 * 256;
  const bf16* Bm = Xt + (size_t)b * 4096 * 256 + (size_t)ct * 128 * 256;
  bf16* dst = Ubuf + (rowbase + (size_t)rt * 128) * 4096 + ct * 128;
  gemm_bt_tile(A, Bm, 256, dst);
}

// ================= 256^2 8-phase bt-GEMM, m201-style schedule =================
// C(256x256) = A(256xK) * B(256xK)^T-rows, ldc=4096. 8 waves (2Mx4N), per-wave 128x64.
// LDS 128KiB: buf{0,1} x {A-h0,A-h1,B-h0,B-h1} x 16KB. T2 swizzle: 16B col-block ^= (row&7),
// pre-swizzled global source + swizzled ds_read (involution both sides, rule #21).
// QUADRANT-MAJOR A halves: A-half h = global tile rows {64h..64h+63} U {128+64h..+63},
// so a half is fully consumed after 2 phases (its 2 quadrants).
// Per phase: [12 or 4 ds_reads] [stage 1 half-tile = 2 GLL16] [lgkm8 if 12] BAR lgkm0
//            setprio1 16xMFMA setprio0 [vmcnt(6) at P3/P7] BAR.
// Stage slots (iter it; tiles 2it->buf0 @P0-3, 2it+1->buf1 @P4-7):
//   P0: A1(b1, t=2it+1)   P1: B0(b0,t+2)  P2: B1(b0,t+2)  P3: A0(b0,t+2) +vmcnt(6|0last)
//   P4: A1(b0,t+2)        P5: B0(b1,t+3)  P6: B1(b1,t+3)  P7: A0(b1,t+3) +vmcnt(6|none)
// WAR: each region staged >=1 end-barrier after its last read's lgkm-drain. RAW: in-order
// vmcnt leaves exactly the 6 newest loads at P3/P7 (invariant verified prologue/steady/last;
// stage-to-read distance 5-7 phases).
template <int EPI>  // 0: Cb = bf16(acc+Db) ; 2: rt<8 -> Cf=acc+Db+bias, rt>=8 -> Cf2=acc
__global__ __launch_bounds__(512, 2) void gemm256(
    const bf16* __restrict__ Aall, const bf16* __restrict__ B0m,
    const bf16* __restrict__ B1m, bf16* __restrict__ Cb, float* __restrict__ Cf,
    float* __restrict__ Cf2, const bf16* __restrict__ Db,
    const float* __restrict__ bias, int K) {
  const int tid = threadIdx.x;
  const int lane = tid & 63;
  const int w = tid >> 6;          // wave 0..7
  const int wr = w >> 2, wc = w & 3;

  // T1: bijective XCD swizzle, 256 blocks
  int bid = blockIdx.x;
  int gid = (bid & 7) * 32 + (bid >> 3);
  const int rt = gid >> 4, ct = gid & 15;

  const bf16* Atile = Aall + (size_t)rt * 256 * K;
  const bf16* Btile = ((rt < 8) ? B0m : B1m) + (size_t)ct * 256 * K;

  __shared__ __align__(16) char lds_[131072];

  // staging: thread covers LDS rows {srow, srow+64} of a 128-row half;
  // source col pre-swizzled by (srow&7) (== LDS row &7 for both rows).
  const int srow = tid >> 3;                                // 0..63
  const int scol = (((tid & 7) ^ (srow & 7)) << 3);         // elements
  const bf16* gAb = Atile + scol;
  const bf16* gBb = Btile + scol;

  // A-half h: LDS row l<64 -> global row 64h+l ; l>=64 -> 128+64h+(l-64)
#define STAGE_A(buf, h, kt)                                                    \
  do {                                                                         \
    char* l = &lds_[(buf)*65536 + (h)*16384 + w * 1024];                       \
    const bf16* g = gAb + (size_t)(64 * (h) + srow) * K + (size_t)(kt)*64;     \
    GLL16(g, l);                                                               \
    GLL16(g + (size_t)128 * K, l + 8192);                                      \
  } while (0)
  // B-half h: LDS row l -> global row 128h + l
#define STAGE_B(buf, h, kt)                                                    \
  do {                                                                         \
    char* l = &lds_[(buf)*65536 + 32768 + (h)*16384 + w * 1024];               \
    const bf16* g = gBb + (size_t)(128 * (h) + srow) * K + (size_t)(kt)*64;    \
    GLL16(g, l);                                                               \
    GLL16(g + (size_t)64 * K, l + 8192);                                       \
  } while (0)

  const int rsel = lane & 15;
  const int cbb = lane >> 4;   // 0..3
  const int xorv = rsel & 7;
  const int aBase = wr * 8192 + rsel * 128;
  const int bBase = 32768 + (wc >> 1) * 16384 + ((wc & 1) * 64 + rsel) * 128;
  // A frag (quadrant q, sub mi, k-slot ks): half q>>1, LDS row wr*64+(q&1)*32+mi*16+rsel
#define LDA(buf, q, mi, ks)                                                    \
  (*(const bshort8*)&lds_[(buf)*65536 + ((q) >> 1) * 16384 + aBase +           \
                          ((q)&1) * 4096 + (mi)*2048 +                         \
                          (((((ks)*4) + cbb) ^ xorv) << 4)])
#define LDB(buf, nf, ks)                                                       \
  (*(const bshort8*)&lds_[(buf)*65536 + bBase + (nf)*2048 +                    \
                          (((((ks)*4) + cbb) ^ xorv) << 4)])

  f32x4 acc[8][4];
#pragma unroll
  for (int i = 0; i < 8; ++i)
#pragma unroll
    for (int j = 0; j < 4; ++j) acc[i][j] = (f32x4){0.f, 0.f, 0.f, 0.f};

  const int NT = K >> 6;   // 64-wide K tiles
  const int NI = NT >> 1;  // iterations (2 tiles each)

  // single-buffered frags (R2-proven; R4's double-buffering spilled)
  bshort8 afr[2][2], bfr[4][2];

#define RD_A(BUF, Q)                                                           \
  do {                                                                         \
    afr[0][0] = LDA(BUF, Q, 0, 0); afr[0][1] = LDA(BUF, Q, 0, 1);              \
    afr[1][0] = LDA(BUF, Q, 1, 0); afr[1][1] = LDA(BUF, Q, 1, 1);              \
  } while (0)
#define RD_B(BUF)                                                              \
  do {                                                                         \
    bfr[0][0] = LDB(BUF, 0, 0); bfr[0][1] = LDB(BUF, 0, 1);                    \
    bfr[1][0] = LDB(BUF, 1, 0); bfr[1][1] = LDB(BUF, 1, 1);                    \
    bfr[2][0] = LDB(BUF, 2, 0); bfr[2][1] = LDB(BUF, 2, 1);                    \
    bfr[3][0] = LDB(BUF, 3, 0); bfr[3][1] = LDB(BUF, 3, 1);                    \
  } while (0)

#define MFMA16(Q)                                                              \
  do {                                                                         \
    _Pragma("unroll") for (int mi = 0; mi < 2; ++mi)                           \
    _Pragma("unroll") for (int nf = 0; nf < 4; ++nf)                           \
    _Pragma("unroll") for (int ks = 0; ks < 2; ++ks)                           \
        acc[(Q)*2 + mi][nf] = __builtin_amdgcn_mfma_f32_16x16x32_bf16(         \
            afr[mi][ks], bfr[nf][ks], acc[(Q)*2 + mi][nf], 0, 0, 0);           \
  } while (0)

#define PHASE(BUF, Q, RDB, STAGESTMT, TAILSTMT)                                \
  do {                                                                         \
    if (RDB) RD_B(BUF);                                                        \
    RD_A(BUF, Q);                                                              \
    STAGESTMT;                                                                 \
    if (RDB) WAIT_LGKM8;                                                       \
    BARRIER;                                                                   \
    WAIT_LGKM0;                                                                \
    __builtin_amdgcn_s_setprio(1);                                             \
    MFMA16(Q);                                                                 \
    __builtin_amdgcn_s_setprio(0);                                             \
    TAILSTMT;                                                                  \
    BARRIER;                                                                   \
  } while (0)

  // prologue: 7 half-tiles (14 loads); vmcnt(6) drains buf0's 8, leaves
  // {B0b1,B1b1,A0b1} = 6 in flight == steady-state invariant at P0.
  STAGE_B(0, 0, 0); STAGE_B(0, 1, 0);
  STAGE_A(0, 0, 0); STAGE_A(0, 1, 0);
  STAGE_B(1, 0, 1); STAGE_B(1, 1, 1);
  STAGE_A(1, 0, 1);
  WAIT_VM(6);
  BARRIER;

  for (int it = 0; it < NI; ++it) {
    const int t1 = 2 * it + 1, t2 = 2 * it + 2, t3 = 2 * it + 3;
    const bool p2v = t2 < NT, p3v = t3 < NT, last = (it == NI - 1);
    PHASE(0, 0, 1, { STAGE_A(1, 1, t1); }, {});
    PHASE(0, 1, 0, { if (p2v) STAGE_B(0, 0, t2); }, {});
    PHASE(0, 2, 0, { if (p2v) STAGE_B(0, 1, t2); }, {});
    PHASE(0, 3, 0, { if (p2v) STAGE_A(0, 0, t2); },
          { if (last) { WAIT_VM(0); } else { WAIT_VM(6); } });
    PHASE(1, 0, 1, { if (p2v) STAGE_A(0, 1, t2); }, {});
    PHASE(1, 1, 0, { if (p3v) STAGE_B(1, 0, t3); }, {});
    PHASE(1, 2, 0, { if (p3v) STAGE_B(1, 1, t3); }, {});
    PHASE(1, 3, 0, { if (p3v) STAGE_A(1, 0, t3); },
          { if (!last) { WAIT_VM(6); } });
  }

  // epilogue: C/D map col=lane&15, row=(lane>>4)*4+reg (verified m89/m91)
  const int colf = lane & 15;
  const int rowf = (lane >> 4) * 4;
  const size_t crow0 = (size_t)rt * 256 + wr * 128;
  const size_t ccol0 = (size_t)ct * 256 + wc * 64;
#pragma unroll
  for (int mf = 0; mf < 8; ++mf) {
#pragma unroll
    for (int nf = 0; nf < 4; ++nf) {
#pragma unroll
      for (int r = 0; r < 4; ++r) {
        size_t row = crow0 + mf * 16 + rowf + r;
        size_t col = ccol0 + nf * 16 + colf;
        size_t off = row * 4096 + col;
        float v = acc[mf][nf][r];
        if constexpr (EPI == 0) {
          v += __bfloat162float(Db[off]);
          Cb[off] = __float2bfloat16(v);
        } else {
          if (rt < 8) {
            v += __bfloat162float(Db[off]) + bias[row & 255];
            Cf[off] = v;
          } else {
            Cf2[(row - 2048) * 4096 + col] = v;
          }
        }
      }
    }
  }
#undef STAGE_A
#undef STAGE_B
#undef LDA
#undef LDB
#undef RD_A
#undef RD_B
#undef MFMA16
#undef PHASE
}

// ---- Y += P1 ----
__global__ __launch_bounds__(256) void reduce_add(float* __restrict__ Y,
                                                  const float* __restrict__ P1) {
  float4* Y4 = (float4*)Y;
  const float4* P4 = (const float4*)P1;
  const int n4 = 2048 * 4096 / 4;
  int stride = gridDim.x * blockDim.x;
  for (int i = blockIdx.x * 256 + threadIdx.x; i < n4; i += stride) {
    float4 a = Y4[i];
    float4 b = P4[i];
    a.x += b.x; a.y += b.y; a.z += b.z; a.w += b.w;
    Y4[i] = a;
  }
}

extern "C" void kernel_launch(void* const* d_in, const int* in_sizes, int n_in,
                              void* d_out, int out_size, void* d_ws, size_t ws_size,
                              hipStream_t stream) {
  const float* Ll = (const float*)d_in[0];
  const float* Lu = (const float*)d_in[1];
  const float* x = (const float*)d_in[2];
  const float* th = (const float*)d_in[3];
  const float* bias = (const float*)d_in[4];
  float* Y = (float*)d_out;

  // Workspace: total 235,798,528 B (< R2-proven 252,575,744; ws_size ~256 MiB).
  char* ws = (char*)d_ws;
  const size_t SZ_L = (size_t)4096 * 4096 * 2;
  const size_t SZ_U = (size_t)4096 * 4096 * 2;
  const size_t SZ_X = (size_t)8 * 4096 * 256 * 2;
  const size_t SZ_T = ((size_t)7 * 256 * 256 * 2 + 255) & ~(size_t)255;
  const size_t SZ_U0 = (size_t)2048 * 4096 * 2;
  bf16* Llb = (bf16*)ws; ws += SZ_L;
  bf16* Lub = (bf16*)ws; ws += SZ_L;
  bf16* Xt  = (bf16*)ws; ws += SZ_X;
  bf16* Tall = (bf16*)ws; ws += SZ_T;
  bf16* U1 = (bf16*)ws; ws += SZ_U;
  bf16* U2 = (bf16*)ws; ws += SZ_U;
  bf16* U3 = (bf16*)ws; ws += SZ_U;   // reused as V2 output of g2
  bf16* U0 = (bf16*)ws; ws += SZ_U0;
  bf16* V1 = (bf16*)ws; ws += SZ_U;
  // P1 aliases V1 (dead after g2); 2048*4096*4 B == SZ_U exactly.
  float* P1 = (float*)V1;
  (void)ws_size; (void)in_sizes; (void)n_in; (void)out_size;

  cast_f32_bf16<<<2048, 256, 0, stream>>>(Ll, Llb, 4096 * 4096 / 4);
  cast_f32_bf16<<<2048, 256, 0, stream>>>(Lu, Lub, 4096 * 4096 / 4);
  transpose_cast_x<<<dim3(64, 4, 8), 256, 0, stream>>>(x, Xt);
  build_theta<<<1792, 256, 0, stream>>>(th, Tall);

  chan_all<<<dim3(2, 32, 56), 256, 0, stream>>>(Tall, Xt, U0, U1, U2, U3);

  gemm256<0><<<256, 512, 0, stream>>>(U3, Llb, Lub, V1, nullptr, nullptr, U2,
                                      nullptr, 4096);  // V1 = L@U3 + U2
  gemm256<0><<<256, 512, 0, stream>>>(V1, Llb, Lub, U3, nullptr, nullptr, U1,
                                      nullptr, 4096);  // V2(=U3) = L@V1 + U1
  gemm256<2><<<256, 512, 0, stream>>>(U3, Llb, Lub, nullptr, Y, P1, U0, bias,
                                      4096);           // Y(chain0)+U0+bias ; P1(chain1)
  reduce_add<<<2048, 256, 0, stream>>>(Y, P1);
}